// Round 7
// baseline (2296.179 us; speedup 1.0000x reference)
//
#include <hip/hip_runtime.h>
#include <hip/hip_bf16.h>

#define HH 51
#define TPB 512     // 8 waves; 1 block/CU. P1: wave=batch elementwise; P2: 39 tile-jobs over 8 waves
#define BPB 8
#define US 36       // unit stride (floats) in gate buffers: f4-aligned, spreads 8 bank-groups
#define MTSZ (52 * US)   // per-matrix gate buffer (52 units: 51 + out row)

typedef _Float16 half8 __attribute__((ext_vector_type(8)));
typedef float f4 __attribute__((ext_vector_type(4)));

// Light barrier: drain LDS only; global stores / reg-dest loads stay in flight.
#define LBAR() asm volatile("s_waitcnt lgkmcnt(0)\ns_barrier" ::: "memory")

__device__ __forceinline__ float bf2f(unsigned short u) {
    return __uint_as_float(((unsigned)u) << 16);
}
__device__ __forceinline__ float loadf(const void* p, size_t i, bool bf) {
    return bf ? bf2f(((const unsigned short*)p)[i]) : ((const float*)p)[i];
}
__device__ __forceinline__ void storef(void* p, size_t i, float v, bool bf) {
    if (bf) ((__hip_bfloat16*)p)[i] = __float2bfloat16(v);
    else    ((float*)p)[i] = v;
}
__device__ __forceinline__ float sigm(float v) {
    float e = __expf(-fabsf(v));
    float s = 1.0f / (1.0f + e);
    return (v >= 0.0f) ? s : 1.0f - s;
}
__device__ __forceinline__ float tanh_fast(float v) {
    float e = __expf(-2.0f * fabsf(v));
    float t = (1.0f - e) / (1.0f + e);
    return (v >= 0.0f) ? t : -t;
}
__device__ __forceinline__ f4 MF(half8 a, half8 b, f4 c) {
    return __builtin_amdgcn_mfma_f32_16x16x32_f16(a, b, c, 0, 0, 0);
}
// wave64 sum via DPP (verified rounds 5-13), result uniform across lanes
__device__ __forceinline__ float wave_sum(float x) {
    float s = x, t;
    t = __builtin_bit_cast(float, __builtin_amdgcn_update_dpp(0, __builtin_bit_cast(int, s), 0x111, 0xf, 0xf, true)); s += t;
    t = __builtin_bit_cast(float, __builtin_amdgcn_update_dpp(0, __builtin_bit_cast(int, s), 0x112, 0xf, 0xf, true)); s += t;
    t = __builtin_bit_cast(float, __builtin_amdgcn_update_dpp(0, __builtin_bit_cast(int, s), 0x114, 0xf, 0xf, true)); s += t;
    t = __builtin_bit_cast(float, __builtin_amdgcn_update_dpp(0, __builtin_bit_cast(int, s), 0x118, 0xf, 0xf, true)); s += t;
    t = __builtin_bit_cast(float, __builtin_amdgcn_update_dpp(0, __builtin_bit_cast(int, s), 0x142, 0xa, 0xf, true)); s += t;
    t = __builtin_bit_cast(float, __builtin_amdgcn_update_dpp(0, __builtin_bit_cast(int, s), 0x143, 0xc, 0xf, true)); s += t;
    return __builtin_bit_cast(float, __builtin_amdgcn_readlane(__builtin_bit_cast(int, s), 63));
}

__global__ __launch_bounds__(TPB, 1) void gru_kernel(
    const void* __restrict__ xg,
    const void* __restrict__ wih1, const void* __restrict__ whh1,
    const void* __restrict__ bih1, const void* __restrict__ bhh1,
    const void* __restrict__ wih2, const void* __restrict__ whh2,
    const void* __restrict__ bih2, const void* __restrict__ bhh2,
    const void* __restrict__ wlin, const void* __restrict__ blin_p,
    void* __restrict__ dout, int T, int TF)
{
    // W rows 4-interleaved: staged row r = 4*unit + gate (gate 3 = pad); 208 rows = 13 tiles.
    __shared__ __align__(16) _Float16 stg[208 * 64];     // 26624 B
    __shared__ __align__(16) float gbufA[3 * MTSZ];      // 22464 B: [mt][unit][batch*4] f4 = (r,z,n,pad)
    __shared__ __align__(16) _Float16 h1b[16 * 72];      // f16 state, k52 = 1 (bias slot)
    __shared__ __align__(16) _Float16 h2b[16 * 72];
    __shared__ float obufL[BPB * 36];

    const int tid = threadIdx.x, w = tid >> 6, lane = tid & 63;
    const int n16 = lane & 15, q = lane >> 4;
    const bool li = lane < HH;
    const int il = li ? lane : HH - 1;
    const int bg0 = blockIdx.x * BPB;
    const int myb = bg0 + w;

    // runtime dtype detection (fp32 vs bf16), uniform
    bool isbf;
    {
        const unsigned short* u = (const unsigned short*)whh1;
        int ok = 1;
#pragma unroll
        for (int k = 0; k < 16; ++k) {
            unsigned e = (u[2 * k] >> 7) & 0xFF;
            ok &= (e >= 100 && e <= 125) ? 1 : 0;
        }
        isbf = (ok != 0);
    }

    // elementwise constants (lane = hidden unit)
    float wr1 = 0, wz1 = 0, wn1 = 0, bn1 = 0, wl = 0;
    if (li) {
        wr1 = loadf(wih1, il, isbf);          wz1 = loadf(wih1, HH + il, isbf);
        wn1 = loadf(wih1, 2 * HH + il, isbf); bn1 = loadf(bih1, 2 * HH + il, isbf);
        wl  = loadf(wlin, il, isbf);
    }
    const float blv = loadf(blin_p, 0, isbf);

    // ---- job table: 39 jobs = 13 tiles x 3 matrices. j<13: mt0 tile j (h1);
    //      13<=j<26: mt2 tile j-13 (h1); 26<=j<39: mt1 tile j-26 (h2).
    //      wave w owns j = 5w + s, s < jn (jn = 5 except wave7: 4).
    const int jn = (w < 7) ? 5 : 4;
    int jmt[5], jtl[5], jdst[5];
#pragma unroll
    for (int s = 0; s < 5; ++s) {
        int j = w * 5 + s;
        int mt = (j < 13) ? 0 : (j < 26) ? 2 : 1;
        int tl = (j < 13) ? j : (j < 26) ? (j - 13) : (j - 26);
        jmt[s] = mt; jtl[s] = tl;
        jdst[s] = ((mt == 0) ? 0 : (mt == 1) ? MTSZ : 2 * MTSZ) + tl * 4 * US;
    }
    const bool needH1 = (w * 5 < 26);
    const bool needH2 = (w * 5 + jn > 26);
    const int laneoff = q * US + 4 * n16;   // store offset for (unit q-of-tile, batch n16)
    const bool stlane = (n16 < 8);

    // ---- stage matrices (f16, 4-interleaved rows; biases at k=52; w_lin/b_lin at row 204 of mt1) ----
    half8 Wf[5][2];
#pragma unroll 1
    for (int mt = 0; mt < 3; ++mt) {
        const void* wm = (mt == 0) ? whh1 : (mt == 1) ? whh2 : wih2;
        for (int e = tid; e < 208 * 64; e += TPB) {
            int r = e >> 6, k = e & 63;
            int u = r >> 2, g = r & 3;
            float v = 0.0f;
            if (u < HH && g < 3) {
                int gr = g * HH + u;
                if (k < HH) v = loadf(wm, (size_t)gr * HH + k, isbf);
                else if (k == 52) {
                    if (mt == 0)      v = loadf(bhh1, gr, isbf) + ((g < 2) ? loadf(bih1, gr, isbf) : 0.0f);
                    else if (mt == 1) v = loadf(bhh2, gr, isbf);
                    else              v = loadf(bih2, gr, isbf);
                }
            } else if (mt == 1 && r == 204) {
                // out row: D[204][b] = wl . h2[b] + blv  (unit 51, gate 0)
                if (k < HH) v = loadf(wlin, k, isbf);
                else if (k == 52) v = blv;
            }
            stg[e] = (_Float16)v;
        }
        __syncthreads();
#pragma unroll
        for (int s = 0; s < 5; ++s) {
            if (s < jn && jmt[s] == mt) {
                int tl = jtl[s];
                Wf[s][0] = *(const half8*)(stg + (size_t)(16 * tl + n16) * 64 + q * 8);
                Wf[s][1] = *(const half8*)(stg + (size_t)(16 * tl + n16) * 64 + 32 + q * 8);
            }
        }
        __syncthreads();
    }

    // ---- init runtime LDS ----
    for (int e = tid; e < 16 * 72; e += TPB) { h1b[e] = (_Float16)0; h2b[e] = (_Float16)0; }
    for (int e = tid; e < 3 * MTSZ; e += TPB) gbufA[e] = 0.0f;

    // x prefetch, double-buffered
    float xreg = 0.0f, xnext = 0.0f;
    if (lane < T) xreg = loadf(xg, (size_t)myb * T + lane, isbf);
    __syncthreads();
    if (tid < 16) { h1b[tid * 72 + 52] = (_Float16)1.0f; h2b[tid * 72 + 52] = (_Float16)1.0f; }
    __syncthreads();

    // ---- prologue: g1(0) from bias-slot h1 — mt0 jobs (waves 0-2) ----
    {
        half8 H0 = *(const half8*)(h1b + n16 * 72 + q * 8);
        half8 H1 = *(const half8*)(h1b + n16 * 72 + 32 + q * 8);
#pragma unroll
        for (int s = 0; s < 5; ++s) {
            if (s < jn && jmt[s] == 0) {
                f4 acc = {0.f, 0.f, 0.f, 0.f};
                acc = MF(Wf[s][0], H0, acc); acc = MF(Wf[s][1], H1, acc);
                if (stlane) *(f4*)(gbufA + jdst[s] + laneoff) = acc;
            }
        }
    }
    __syncthreads();

    float h1p = 0.0f, h2p = 0.0f;
    const float* gl = gbufA + il * US + 4 * w;   // per-lane gate pointer: f4 (r,z,n,pad)
    const int orow = MTSZ + 51 * US;             // out row: gbufA[orow + 4*b]

    // ================= ENCODE loop =================
    for (int t = 0; t < T; ++t) {
        // ---- P1: e1(t) + e2(t-1) ----
        f4 G1 = *(const f4*)gl;
        float xv = __builtin_bit_cast(float, __builtin_amdgcn_readlane(__builtin_bit_cast(int, xreg), t & 63));
        {
            float r = sigm(fmaf(xv, wr1, G1[0]));
            float z = sigm(fmaf(xv, wz1, G1[1]));
            float n = tanh_fast(fmaf(xv, wn1, bn1) + r * G1[2]);
            float h = n + z * (h1p - n); h1p = h;
            if (li) h1b[w * 72 + il] = (_Float16)h;
        }
        if (t > 0) {
            f4 GH = *(const f4*)(gl + MTSZ);
            f4 GI = *(const f4*)(gl + 2 * MTSZ);
            float r2 = sigm(GI[0] + GH[0]), z2 = sigm(GI[1] + GH[1]);
            float n2 = tanh_fast(GI[2] + r2 * GH[2]);
            float h = n2 + z2 * (h2p - n2); h2p = h;
            if (li) h2b[w * 72 + il] = (_Float16)h;
        }
        // out(t-2) from the folded row (produced by mt1 matmul at step t-1)
        if (lane == 0 && t >= 2)
            obufL[w * 36 + ((t - 2) & 31)] = gbufA[orow + 4 * w];
        LBAR();

        // ---- P2: 39 tile-jobs, W in registers (A), h fragments (B) ----
        {
            half8 H10 = {}, H11 = {}, H20 = {}, H21 = {};
            if (needH1) {
                H10 = *(const half8*)(h1b + n16 * 72 + q * 8);
                H11 = *(const half8*)(h1b + n16 * 72 + 32 + q * 8);
            }
            if (needH2) {
                H20 = *(const half8*)(h2b + n16 * 72 + q * 8);
                H21 = *(const half8*)(h2b + n16 * 72 + 32 + q * 8);
            }
#pragma unroll
            for (int s = 0; s < 5; ++s) {
                if (s < jn) {
                    half8 B0 = (jmt[s] == 1) ? H20 : H10;
                    half8 B1 = (jmt[s] == 1) ? H21 : H11;
                    f4 acc = {0.f, 0.f, 0.f, 0.f};
                    acc = MF(Wf[s][0], B0, acc); acc = MF(Wf[s][1], B1, acc);
                    if (stlane) *(f4*)(gbufA + jdst[s] + laneoff) = acc;
                }
            }
        }
        // waves 6,7 flush outputs [t-33 .. t-2]
        if (w >= 6 && (t & 31) == 1 && t > 32) {
            int fb = t - 33;
#pragma unroll
            for (int k2 = 0; k2 < 2; ++k2) {
                int et = ((w - 6) << 7) + (k2 << 6) + lane;   // 0..255
                int b = et >> 5, tt = et & 31;
                storef(dout, (size_t)(bg0 + b) * TF + fb + tt, obufL[b * 36 + tt], isbf);
            }
        }
        // x double-buffer
        if ((t & 63) == 0) {
            int base = t + 64;
            if (base < T) {
                int src = base + lane;
                xnext = (src < T) ? loadf(xg, (size_t)myb * T + src, isbf) : 0.0f;
            }
        } else if ((t & 63) == 63) {
            xreg = xnext;
        }
        LBAR();
    }

    // ================= FEEDBACK loop =================
    for (int t = T; t < TF; ++t) {
        // ---- P1: e2(t-1) -> out(t-1) -> e1(t) ----
        f4 G1 = *(const f4*)gl;
        if (t == T && lane == 0)   // patch out(T-2) still owed by the folded row
            obufL[w * 36 + ((t - 2) & 31)] = gbufA[orow + 4 * w];
        {
            f4 GH = *(const f4*)(gl + MTSZ);
            f4 GI = *(const f4*)(gl + 2 * MTSZ);
            float r2 = sigm(GI[0] + GH[0]), z2 = sigm(GI[1] + GH[1]);
            float n2 = tanh_fast(GI[2] + r2 * GH[2]);
            float h = n2 + z2 * (h2p - n2); h2p = h;
            float p = 0.0f;
            if (li) {
                h2b[w * 72 + il] = (_Float16)h;
                p = h * wl;
            }
            float outv = wave_sum(p) + blv;
            if (lane == 0) obufL[w * 36 + ((t - 1) & 31)] = outv;
            float r = sigm(fmaf(outv, wr1, G1[0]));
            float z = sigm(fmaf(outv, wz1, G1[1]));
            float n = tanh_fast(fmaf(outv, wn1, bn1) + r * G1[2]);
            float h1 = n + z * (h1p - n); h1p = h1;
            if (li) h1b[w * 72 + il] = (_Float16)h1;
        }
        LBAR();
        // ---- P2 ----
        {
            half8 H10 = {}, H11 = {}, H20 = {}, H21 = {};
            if (needH1) {
                H10 = *(const half8*)(h1b + n16 * 72 + q * 8);
                H11 = *(const half8*)(h1b + n16 * 72 + 32 + q * 8);
            }
            if (needH2) {
                H20 = *(const half8*)(h2b + n16 * 72 + q * 8);
                H21 = *(const half8*)(h2b + n16 * 72 + 32 + q * 8);
            }
#pragma unroll
            for (int s = 0; s < 5; ++s) {
                if (s < jn) {
                    half8 B0 = (jmt[s] == 1) ? H20 : H10;
                    half8 B1 = (jmt[s] == 1) ? H21 : H11;
                    f4 acc = {0.f, 0.f, 0.f, 0.f};
                    acc = MF(Wf[s][0], B0, acc); acc = MF(Wf[s][1], B1, acc);
                    if (stlane) *(f4*)(gbufA + jdst[s] + laneoff) = acc;
                }
            }
        }
        if (w >= 6 && (t & 31) == 0) {   // flush [t-32 .. t-1]
            int fb = t - 32;
#pragma unroll
            for (int k2 = 0; k2 < 2; ++k2) {
                int et = ((w - 6) << 7) + (k2 << 6) + lane;
                int b = et >> 5, tt = et & 31;
                storef(dout, (size_t)(bg0 + b) * TF + fb + tt, obufL[b * 36 + tt], isbf);
            }
        }
        LBAR();
    }

    // ---- epilogue: e2(TF-1) + out(TF-1) + tail flush ----
    {
        f4 GH = *(const f4*)(gl + MTSZ);
        f4 GI = *(const f4*)(gl + 2 * MTSZ);
        float p = 0.0f;
        float r2 = sigm(GI[0] + GH[0]), z2 = sigm(GI[1] + GH[1]);
        float n2 = tanh_fast(GI[2] + r2 * GH[2]);
        float h = n2 + z2 * (h2p - n2);
        if (li) p = h * wl;
        float osum = wave_sum(p) + blv;
        if (lane == 0) obufL[w * 36 + ((TF - 1) & 31)] = osum;
    }
    __syncthreads();
    {
        int base = (TF - 1) & ~31, rem = TF - base;
        if (tid < BPB * 32) {
            int b = tid >> 5, tt = tid & 31;
            if (tt < rem)
                storef(dout, (size_t)(bg0 + b) * TF + base + tt, obufL[b * 36 + tt], isbf);
        }
    }
}

extern "C" void kernel_launch(void* const* d_in, const int* in_sizes, int n_in,
                              void* d_out, int out_size, void* d_ws, size_t ws_size,
                              hipStream_t stream) {
    const int B = 2048;
    const int T = in_sizes[0] / B;   // 1000
    const int TF = out_size / B;     // 2000
    gru_kernel<<<dim3(B / BPB), dim3(TPB), 0, stream>>>(
        d_in[0], d_in[1], d_in[2], d_in[3], d_in[4], d_in[5],
        d_in[6], d_in[7], d_in[8], d_in[9], d_in[10],
        d_out, T, TF);
}

// Round 8
// 1843.143 us; speedup vs baseline: 1.2458x; 1.2458x over previous
//
#include <hip/hip_runtime.h>
#include <hip/hip_bf16.h>

#define HH 51
#define TPB 512     // 8 waves; 1 block/CU. P1: wave=batch elementwise; P2: 39 tile-jobs over 8 waves
#define BPB 8
#define US 36       // unit stride (floats) in gate buffers: f4-aligned, spreads 8 bank-groups
#define MTSZ (52 * US)   // per-matrix gate buffer (52 units: 51 + out row)

typedef _Float16 half8 __attribute__((ext_vector_type(8)));
typedef float f4 __attribute__((ext_vector_type(4)));

// Light barrier: drain LDS only; global stores / reg-dest loads stay in flight.
#define LBAR() asm volatile("s_waitcnt lgkmcnt(0)\ns_barrier" ::: "memory")

__device__ __forceinline__ float bf2f(unsigned short u) {
    return __uint_as_float(((unsigned)u) << 16);
}
__device__ __forceinline__ float loadf(const void* p, size_t i, bool bf) {
    return bf ? bf2f(((const unsigned short*)p)[i]) : ((const float*)p)[i];
}
__device__ __forceinline__ void storef(void* p, size_t i, float v, bool bf) {
    if (bf) ((__hip_bfloat16*)p)[i] = __float2bfloat16(v);
    else    ((float*)p)[i] = v;
}
// 4-instr sigmoid: rcp(1+exp(-v)). v->+inf: exp->0, rcp(1)=1. v->-inf: exp->inf, rcp->0.
__device__ __forceinline__ float sigm(float v) {
    return __builtin_amdgcn_rcpf(1.0f + __expf(-v));
}
// 5-instr tanh: 2*rcp(1+exp(-2v)) - 1. Exact at 0 (rcp(2)=0.5); correct limits.
__device__ __forceinline__ float tanh_fast(float v) {
    return fmaf(2.0f, __builtin_amdgcn_rcpf(1.0f + __expf(-2.0f * v)), -1.0f);
}
__device__ __forceinline__ f4 MF(half8 a, half8 b, f4 c) {
    return __builtin_amdgcn_mfma_f32_16x16x32_f16(a, b, c, 0, 0, 0);
}
// wave64 sum via DPP (verified rounds 5-13), result uniform across lanes
__device__ __forceinline__ float wave_sum(float x) {
    float s = x, t;
    t = __builtin_bit_cast(float, __builtin_amdgcn_update_dpp(0, __builtin_bit_cast(int, s), 0x111, 0xf, 0xf, true)); s += t;
    t = __builtin_bit_cast(float, __builtin_amdgcn_update_dpp(0, __builtin_bit_cast(int, s), 0x112, 0xf, 0xf, true)); s += t;
    t = __builtin_bit_cast(float, __builtin_amdgcn_update_dpp(0, __builtin_bit_cast(int, s), 0x114, 0xf, 0xf, true)); s += t;
    t = __builtin_bit_cast(float, __builtin_amdgcn_update_dpp(0, __builtin_bit_cast(int, s), 0x118, 0xf, 0xf, true)); s += t;
    t = __builtin_bit_cast(float, __builtin_amdgcn_update_dpp(0, __builtin_bit_cast(int, s), 0x142, 0xa, 0xf, true)); s += t;
    t = __builtin_bit_cast(float, __builtin_amdgcn_update_dpp(0, __builtin_bit_cast(int, s), 0x143, 0xc, 0xf, true)); s += t;
    return __builtin_bit_cast(float, __builtin_amdgcn_readlane(__builtin_bit_cast(int, s), 63));
}

__global__ __launch_bounds__(TPB, 1) void gru_kernel(
    const void* __restrict__ xg,
    const void* __restrict__ wih1, const void* __restrict__ whh1,
    const void* __restrict__ bih1, const void* __restrict__ bhh1,
    const void* __restrict__ wih2, const void* __restrict__ whh2,
    const void* __restrict__ bih2, const void* __restrict__ bhh2,
    const void* __restrict__ wlin, const void* __restrict__ blin_p,
    void* __restrict__ dout, int T, int TF)
{
    // W rows 4-interleaved: staged row r = 4*unit + gate (gate 3 = pad); 208 rows = 13 tiles.
    __shared__ __align__(16) _Float16 stg[208 * 64];     // 26624 B
    __shared__ __align__(16) float gbufA[3 * MTSZ];      // 22464 B: [mt][unit][batch*4] f4 = (r,z,n,pad)
    __shared__ __align__(16) _Float16 h1b[16 * 72];      // f16 state, k52 = 1 (bias slot)
    __shared__ __align__(16) _Float16 h2b[16 * 72];
    __shared__ float obufL[BPB * 36];

    const int tid = threadIdx.x, w = tid >> 6, lane = tid & 63;
    const int n16 = lane & 15, q = lane >> 4;
    const bool li = lane < HH;
    const int il = li ? lane : HH - 1;
    const int bg0 = blockIdx.x * BPB;
    const int myb = bg0 + w;

    // runtime dtype detection (fp32 vs bf16), uniform
    bool isbf;
    {
        const unsigned short* u = (const unsigned short*)whh1;
        int ok = 1;
#pragma unroll
        for (int k = 0; k < 16; ++k) {
            unsigned e = (u[2 * k] >> 7) & 0xFF;
            ok &= (e >= 100 && e <= 125) ? 1 : 0;
        }
        isbf = (ok != 0);
    }

    // elementwise constants (lane = hidden unit)
    float wr1 = 0, wz1 = 0, wn1 = 0, bn1 = 0, wl = 0;
    if (li) {
        wr1 = loadf(wih1, il, isbf);          wz1 = loadf(wih1, HH + il, isbf);
        wn1 = loadf(wih1, 2 * HH + il, isbf); bn1 = loadf(bih1, 2 * HH + il, isbf);
        wl  = loadf(wlin, il, isbf);
    }
    const float blv = loadf(blin_p, 0, isbf);

    // ---- job table: 39 jobs = 13 tiles x 3 matrices, ordered [mt0 x13][mt2 x13][mt1 x13]
    //      (both h1-consumers first). Wave w owns j = 5w+s, s < jn (jn=5, wave7: 4).
    //      First nH jobs of each wave consume h1; the rest consume h2 (mt1).
    const int jn = (w < 7) ? 5 : 4;
    int nH = 26 - w * 5; nH = (nH < 0) ? 0 : (nH > jn ? jn : nH);
    int jmt[5], jtl[5], jdst[5];
#pragma unroll
    for (int s = 0; s < 5; ++s) {
        int j = w * 5 + s;
        int mt = (j < 13) ? 0 : (j < 26) ? 2 : 1;
        int tl = (j < 13) ? j : (j < 26) ? (j - 13) : (j - 26);
        jmt[s] = mt; jtl[s] = tl;
        jdst[s] = ((mt == 0) ? 0 : (mt == 1) ? MTSZ : 2 * MTSZ) + tl * 4 * US;
    }
    const int laneoff = q * US + 4 * n16;   // store offset for (unit q-of-tile, batch n16)
    const bool stlane = (n16 < 8);

    // ---- stage matrices (f16, 4-interleaved rows; biases at k=52; w_lin/b_lin at row 204 of mt1) ----
    half8 Wf[5][2];
#pragma unroll 1
    for (int mt = 0; mt < 3; ++mt) {
        const void* wm = (mt == 0) ? whh1 : (mt == 1) ? whh2 : wih2;
        for (int e = tid; e < 208 * 64; e += TPB) {
            int r = e >> 6, k = e & 63;
            int u = r >> 2, g = r & 3;
            float v = 0.0f;
            if (u < HH && g < 3) {
                int gr = g * HH + u;
                if (k < HH) v = loadf(wm, (size_t)gr * HH + k, isbf);
                else if (k == 52) {
                    if (mt == 0)      v = loadf(bhh1, gr, isbf) + ((g < 2) ? loadf(bih1, gr, isbf) : 0.0f);
                    else if (mt == 1) v = loadf(bhh2, gr, isbf);
                    else              v = loadf(bih2, gr, isbf);
                }
            } else if (mt == 1 && r == 204) {
                // out row: D[204][b] = wl . h2[b] + blv  (unit 51, gate 0)
                if (k < HH) v = loadf(wlin, k, isbf);
                else if (k == 52) v = blv;
            }
            stg[e] = (_Float16)v;
        }
        __syncthreads();
#pragma unroll
        for (int s = 0; s < 5; ++s) {
            if (s < jn && jmt[s] == mt) {
                int tl = jtl[s];
                Wf[s][0] = *(const half8*)(stg + (size_t)(16 * tl + n16) * 64 + q * 8);
                Wf[s][1] = *(const half8*)(stg + (size_t)(16 * tl + n16) * 64 + 32 + q * 8);
            }
        }
        __syncthreads();
    }

    // ---- init runtime LDS ----
    for (int e = tid; e < 16 * 72; e += TPB) { h1b[e] = (_Float16)0; h2b[e] = (_Float16)0; }
    for (int e = tid; e < 3 * MTSZ; e += TPB) gbufA[e] = 0.0f;

    // x prefetch, double-buffered
    float xreg = 0.0f, xnext = 0.0f;
    if (lane < T) xreg = loadf(xg, (size_t)myb * T + lane, isbf);
    __syncthreads();
    if (tid < 16) { h1b[tid * 72 + 52] = (_Float16)1.0f; h2b[tid * 72 + 52] = (_Float16)1.0f; }
    __syncthreads();

    // ---- prologue: g1(0) from bias-slot h1 — mt0 jobs (waves 0-2) ----
    {
        half8 H0 = *(const half8*)(h1b + n16 * 72 + q * 8);
        half8 H1 = *(const half8*)(h1b + n16 * 72 + 32 + q * 8);
#pragma unroll
        for (int s = 0; s < 5; ++s) {
            if (s < jn && jmt[s] == 0) {
                f4 acc = {0.f, 0.f, 0.f, 0.f};
                acc = MF(Wf[s][0], H0, acc); acc = MF(Wf[s][1], H1, acc);
                if (stlane) *(f4*)(gbufA + jdst[s] + laneoff) = acc;
            }
        }
    }
    __syncthreads();

    float h1p = 0.0f, h2p = 0.0f;
    const float* gl = gbufA + il * US + 4 * w;   // per-lane gate pointer: f4 (r,z,n,pad)
    const int orow = MTSZ + 51 * US;             // out row: gbufA[orow + 4*b]

    // ================= ENCODE loop =================
    for (int t = 0; t < T; ++t) {
        // ---- P1: e1(t) + e2(t-1) ----
        f4 G1 = *(const f4*)gl;
        float xv = __builtin_bit_cast(float, __builtin_amdgcn_readlane(__builtin_bit_cast(int, xreg), t & 63));
        {
            float r = sigm(fmaf(xv, wr1, G1[0]));
            float z = sigm(fmaf(xv, wz1, G1[1]));
            float n = tanh_fast(fmaf(r, G1[2], fmaf(xv, wn1, bn1)));
            float h = fmaf(z, h1p - n, n); h1p = h;
            if (li) h1b[w * 72 + il] = (_Float16)h;
        }
        if (t > 0) {
            f4 GH = *(const f4*)(gl + MTSZ);
            f4 GI = *(const f4*)(gl + 2 * MTSZ);
            float r2 = sigm(GI[0] + GH[0]), z2 = sigm(GI[1] + GH[1]);
            float n2 = tanh_fast(fmaf(r2, GH[2], GI[2]));
            float h = fmaf(z2, h2p - n2, n2); h2p = h;
            if (li) h2b[w * 72 + il] = (_Float16)h;
        }
        // out(t-2) from the folded row (produced by mt1 matmul at step t-1)
        if (lane == 0 && t >= 2)
            obufL[w * 36 + ((t - 2) & 31)] = gbufA[orow + 4 * w];
        LBAR();

        // ---- P2: 39 tile-jobs; h1-jobs then h2-jobs, static operands per loop ----
        {
            half8 H10 = {}, H11 = {}, H20 = {}, H21 = {};
            if (nH > 0) {
                H10 = *(const half8*)(h1b + n16 * 72 + q * 8);
                H11 = *(const half8*)(h1b + n16 * 72 + 32 + q * 8);
            }
            if (nH < jn) {
                H20 = *(const half8*)(h2b + n16 * 72 + q * 8);
                H21 = *(const half8*)(h2b + n16 * 72 + 32 + q * 8);
            }
#pragma unroll
            for (int s = 0; s < 5; ++s) {
                if (s < nH) {
                    f4 acc = {0.f, 0.f, 0.f, 0.f};
                    acc = MF(Wf[s][0], H10, acc); acc = MF(Wf[s][1], H11, acc);
                    if (stlane) *(f4*)(gbufA + jdst[s] + laneoff) = acc;
                }
            }
#pragma unroll
            for (int s = 0; s < 5; ++s) {
                if (s >= nH && s < jn) {
                    f4 acc = {0.f, 0.f, 0.f, 0.f};
                    acc = MF(Wf[s][0], H20, acc); acc = MF(Wf[s][1], H21, acc);
                    if (stlane) *(f4*)(gbufA + jdst[s] + laneoff) = acc;
                }
            }
        }
        // waves 6,7 flush outputs [t-33 .. t-2]
        if (w >= 6 && (t & 31) == 1 && t > 32) {
            int fb = t - 33;
#pragma unroll
            for (int k2 = 0; k2 < 2; ++k2) {
                int et = ((w - 6) << 7) + (k2 << 6) + lane;   // 0..255
                int b = et >> 5, tt = et & 31;
                storef(dout, (size_t)(bg0 + b) * TF + fb + tt, obufL[b * 36 + tt], isbf);
            }
        }
        // x double-buffer
        if ((t & 63) == 0) {
            int base = t + 64;
            if (base < T) {
                int src = base + lane;
                xnext = (src < T) ? loadf(xg, (size_t)myb * T + src, isbf) : 0.0f;
            }
        } else if ((t & 63) == 63) {
            xreg = xnext;
        }
        LBAR();
    }

    // ================= FEEDBACK loop =================
    for (int t = T; t < TF; ++t) {
        // ---- P1: e2(t-1) -> out(t-1) -> e1(t) ----
        f4 G1 = *(const f4*)gl;
        if (t == T && lane == 0)   // patch out(T-2) still owed by the folded row
            obufL[w * 36 + ((t - 2) & 31)] = gbufA[orow + 4 * w];
        {
            f4 GH = *(const f4*)(gl + MTSZ);
            f4 GI = *(const f4*)(gl + 2 * MTSZ);
            float r2 = sigm(GI[0] + GH[0]), z2 = sigm(GI[1] + GH[1]);
            float n2 = tanh_fast(fmaf(r2, GH[2], GI[2]));
            float h = fmaf(z2, h2p - n2, n2); h2p = h;
            float p = 0.0f;
            if (li) {
                h2b[w * 72 + il] = (_Float16)h;
                p = h * wl;
            }
            float outv = wave_sum(p) + blv;
            if (lane == 0) obufL[w * 36 + ((t - 1) & 31)] = outv;
            float r = sigm(fmaf(outv, wr1, G1[0]));
            float z = sigm(fmaf(outv, wz1, G1[1]));
            float n = tanh_fast(fmaf(r, G1[2], fmaf(outv, wn1, bn1)));
            float h1 = fmaf(z, h1p - n, n); h1p = h1;
            if (li) h1b[w * 72 + il] = (_Float16)h1;
        }
        LBAR();
        // ---- P2 ----
        {
            half8 H10 = {}, H11 = {}, H20 = {}, H21 = {};
            if (nH > 0) {
                H10 = *(const half8*)(h1b + n16 * 72 + q * 8);
                H11 = *(const half8*)(h1b + n16 * 72 + 32 + q * 8);
            }
            if (nH < jn) {
                H20 = *(const half8*)(h2b + n16 * 72 + q * 8);
                H21 = *(const half8*)(h2b + n16 * 72 + 32 + q * 8);
            }
#pragma unroll
            for (int s = 0; s < 5; ++s) {
                if (s < nH) {
                    f4 acc = {0.f, 0.f, 0.f, 0.f};
                    acc = MF(Wf[s][0], H10, acc); acc = MF(Wf[s][1], H11, acc);
                    if (stlane) *(f4*)(gbufA + jdst[s] + laneoff) = acc;
                }
            }
#pragma unroll
            for (int s = 0; s < 5; ++s) {
                if (s >= nH && s < jn) {
                    f4 acc = {0.f, 0.f, 0.f, 0.f};
                    acc = MF(Wf[s][0], H20, acc); acc = MF(Wf[s][1], H21, acc);
                    if (stlane) *(f4*)(gbufA + jdst[s] + laneoff) = acc;
                }
            }
        }
        if (w >= 6 && (t & 31) == 0) {   // flush [t-32 .. t-1]
            int fb = t - 32;
#pragma unroll
            for (int k2 = 0; k2 < 2; ++k2) {
                int et = ((w - 6) << 7) + (k2 << 6) + lane;
                int b = et >> 5, tt = et & 31;
                storef(dout, (size_t)(bg0 + b) * TF + fb + tt, obufL[b * 36 + tt], isbf);
            }
        }
        LBAR();
    }

    // ---- epilogue: e2(TF-1) + out(TF-1) + tail flush ----
    {
        f4 GH = *(const f4*)(gl + MTSZ);
        f4 GI = *(const f4*)(gl + 2 * MTSZ);
        float p = 0.0f;
        float r2 = sigm(GI[0] + GH[0]), z2 = sigm(GI[1] + GH[1]);
        float n2 = tanh_fast(fmaf(r2, GH[2], GI[2]));
        float h = fmaf(z2, h2p - n2, n2);
        if (li) p = h * wl;
        float osum = wave_sum(p) + blv;
        if (lane == 0) obufL[w * 36 + ((TF - 1) & 31)] = osum;
    }
    __syncthreads();
    {
        int base = (TF - 1) & ~31, rem = TF - base;
        if (tid < BPB * 32) {
            int b = tid >> 5, tt = tid & 31;
            if (tt < rem)
                storef(dout, (size_t)(bg0 + b) * TF + base + tt, obufL[b * 36 + tt], isbf);
        }
    }
}

extern "C" void kernel_launch(void* const* d_in, const int* in_sizes, int n_in,
                              void* d_out, int out_size, void* d_ws, size_t ws_size,
                              hipStream_t stream) {
    const int B = 2048;
    const int T = in_sizes[0] / B;   // 1000
    const int TF = out_size / B;     // 2000
    gru_kernel<<<dim3(B / BPB), dim3(TPB), 0, stream>>>(
        d_in[0], d_in[1], d_in[2], d_in[3], d_in[4], d_in[5],
        d_in[6], d_in[7], d_in[8], d_in[9], d_in[10],
        d_out, T, TF);
}

// Round 9
// 1783.003 us; speedup vs baseline: 1.2878x; 1.0337x over previous
//
#include <hip/hip_runtime.h>
#include <hip/hip_bf16.h>

#define HH 51
#define TPB 512     // 8 waves; 1 block/CU. P1: wave=batch elementwise; P2: 26 tile-jobs (13 M1 + 13 M2)
#define BPB 8
#define US 36       // unit stride (floats) in gate buffers: f4-aligned, spreads 8 bank-groups

typedef _Float16 half8 __attribute__((ext_vector_type(8)));
typedef float f4 __attribute__((ext_vector_type(4)));

// Light barrier: drain LDS only; global stores / reg-dest loads stay in flight.
#define LBAR() asm volatile("s_waitcnt lgkmcnt(0)\ns_barrier" ::: "memory")

__device__ __forceinline__ float bf2f(unsigned short u) {
    return __uint_as_float(((unsigned)u) << 16);
}
__device__ __forceinline__ float loadf(const void* p, size_t i, bool bf) {
    return bf ? bf2f(((const unsigned short*)p)[i]) : ((const float*)p)[i];
}
__device__ __forceinline__ void storef(void* p, size_t i, float v, bool bf) {
    if (bf) ((__hip_bfloat16*)p)[i] = __float2bfloat16(v);
    else    ((float*)p)[i] = v;
}
// 4-instr sigmoid: rcp(1+exp(-v))
__device__ __forceinline__ float sigm(float v) {
    return __builtin_amdgcn_rcpf(1.0f + __expf(-v));
}
// 5-instr tanh: 2*rcp(1+exp(-2v)) - 1
__device__ __forceinline__ float tanh_fast(float v) {
    return fmaf(2.0f, __builtin_amdgcn_rcpf(1.0f + __expf(-2.0f * v)), -1.0f);
}
__device__ __forceinline__ f4 MF(half8 a, half8 b, f4 c) {
    return __builtin_amdgcn_mfma_f32_16x16x32_f16(a, b, c, 0, 0, 0);
}
// wave64 sum via DPP (verified), result uniform across lanes
__device__ __forceinline__ float wave_sum(float x) {
    float s = x, t;
    t = __builtin_bit_cast(float, __builtin_amdgcn_update_dpp(0, __builtin_bit_cast(int, s), 0x111, 0xf, 0xf, true)); s += t;
    t = __builtin_bit_cast(float, __builtin_amdgcn_update_dpp(0, __builtin_bit_cast(int, s), 0x112, 0xf, 0xf, true)); s += t;
    t = __builtin_bit_cast(float, __builtin_amdgcn_update_dpp(0, __builtin_bit_cast(int, s), 0x114, 0xf, 0xf, true)); s += t;
    t = __builtin_bit_cast(float, __builtin_amdgcn_update_dpp(0, __builtin_bit_cast(int, s), 0x118, 0xf, 0xf, true)); s += t;
    t = __builtin_bit_cast(float, __builtin_amdgcn_update_dpp(0, __builtin_bit_cast(int, s), 0x142, 0xa, 0xf, true)); s += t;
    t = __builtin_bit_cast(float, __builtin_amdgcn_update_dpp(0, __builtin_bit_cast(int, s), 0x143, 0xc, 0xf, true)); s += t;
    return __builtin_bit_cast(float, __builtin_amdgcn_readlane(__builtin_bit_cast(int, s), 63));
}
__device__ __forceinline__ float rdlane(float v, int idx) {
    return __builtin_bit_cast(float, __builtin_amdgcn_readlane(__builtin_bit_cast(int, v), idx));
}

__global__ __launch_bounds__(TPB, 1) void gru_kernel(
    const void* __restrict__ xg,
    const void* __restrict__ wih1, const void* __restrict__ whh1,
    const void* __restrict__ bih1, const void* __restrict__ bhh1,
    const void* __restrict__ wih2, const void* __restrict__ whh2,
    const void* __restrict__ bih2, const void* __restrict__ bhh2,
    const void* __restrict__ wlin, const void* __restrict__ blin_p,
    void* __restrict__ dout, int T, int TF)
{
    // Rows 4-interleaved: staged row r = 4*unit + slot; slots per unit:
    //  M1: (r_full, z_full, n_h, n_i)  — wih1 in col53, biases col52, Whh1 cols 0-50
    //  M2: (r2, z2, n2_h, n2_i) over K=128: [h2(0-50)|bias52|0 ; h1(64-114)]; out row 204
    __shared__ __align__(16) _Float16 stg[208 * 64];     // 26624 B (staged 3x)
    __shared__ __align__(16) float gbuf1[52 * US];       // 7488 B: layer-1 gates f4/unit/batch
    __shared__ __align__(16) float gbuf2[52 * US];       // 7488 B: layer-2 gates + out @ unit 51
    __shared__ __align__(16) _Float16 h1b[16 * 72];      // k52 = 1 (bias), k53 = x(t+1) fold
    __shared__ __align__(16) _Float16 h2b[16 * 72];      // k52 = 1
    __shared__ float obufL[BPB * 36];

    const int tid = threadIdx.x, w = tid >> 6, lane = tid & 63;
    const int n16 = lane & 15, q = lane >> 4;
    const bool li = lane < HH;
    const int il = li ? lane : HH - 1;
    const int bg0 = blockIdx.x * BPB;
    const int myb = bg0 + w;

    // runtime dtype detection (fp32 vs bf16), uniform
    bool isbf;
    {
        const unsigned short* u = (const unsigned short*)whh1;
        int ok = 1;
#pragma unroll
        for (int k = 0; k < 16; ++k) {
            unsigned e = (u[2 * k] >> 7) & 0xFF;
            ok &= (e >= 100 && e <= 125) ? 1 : 0;
        }
        isbf = (ok != 0);
    }

    // lane consts (feedback path + out)
    float wr1 = 0, wz1 = 0, wn1 = 0, wl = 0;
    if (li) {
        wr1 = loadf(wih1, il, isbf);          wz1 = loadf(wih1, HH + il, isbf);
        wn1 = loadf(wih1, 2 * HH + il, isbf); wl = loadf(wlin, il, isbf);
    }
    const float blv = loadf(blin_p, 0, isbf);

    // ---- job split: 13 M1 tiles + 13 M2 tiles over 8 waves ----
    const int nM1 = (w < 3) ? 3 : (w < 5) ? 2 : 0;
    const int bM1 = (w < 3) ? w * 3 : 9 + (w - 3) * 2;            // w0:0 w1:3 w2:6 w3:9 w4:11
    const int nM2 = (w < 4) ? 1 : (w < 7) ? 2 : 3;
    const int bM2 = (w < 4) ? w : (w < 7) ? 4 + (w - 4) * 2 : 10; // w0-3:0-3 w4:4 w5:6 w6:8 w7:10
    const int laneoff = q * US + 4 * n16;
    const bool stlane = (n16 < 8);

    half8 WfM1[3][2], WfM2[3][4];

    // ---- stage: pass0 = M1 (K 0-63); pass1 = M2 K 0-63 (h2 half); pass2 = M2 K 64-127 (h1 half) ----
#pragma unroll 1
    for (int ps = 0; ps < 3; ++ps) {
        for (int e = tid; e < 208 * 64; e += TPB) {
            int r = e >> 6, k = e & 63;
            int u = r >> 2, g = r & 3;
            float v = 0.0f;
            if (ps == 0) {
                if (u < HH) {
                    if (g < 2) {
                        int gr = g * HH + u;
                        if (k < HH) v = loadf(whh1, (size_t)gr * HH + k, isbf);
                        else if (k == 52) v = loadf(bhh1, gr, isbf) + loadf(bih1, gr, isbf);
                        else if (k == 53) v = loadf(wih1, gr, isbf);
                    } else if (g == 2) {
                        int gr = 2 * HH + u;
                        if (k < HH) v = loadf(whh1, (size_t)gr * HH + k, isbf);
                        else if (k == 52) v = loadf(bhh1, gr, isbf);
                    } else {
                        int gr = 2 * HH + u;
                        if (k == 52) v = loadf(bih1, gr, isbf);
                        else if (k == 53) v = loadf(wih1, gr, isbf);
                    }
                }
            } else if (ps == 1) {
                if (u < HH) {
                    if (g < 2) {
                        int gr = g * HH + u;
                        if (k < HH) v = loadf(whh2, (size_t)gr * HH + k, isbf);
                        else if (k == 52) v = loadf(bhh2, gr, isbf) + loadf(bih2, gr, isbf);
                    } else if (g == 2) {
                        int gr = 2 * HH + u;
                        if (k < HH) v = loadf(whh2, (size_t)gr * HH + k, isbf);
                        else if (k == 52) v = loadf(bhh2, gr, isbf);
                    } else {
                        if (k == 52) v = loadf(bih2, 2 * HH + u, isbf);
                    }
                } else if (r == 204) {   // out row: wl . h2 + blv
                    if (k < HH) v = loadf(wlin, k, isbf);
                    else if (k == 52) v = blv;
                }
            } else {
                if (u < HH) {
                    if (g < 2) {
                        if (k < HH) v = loadf(wih2, (size_t)(g * HH + u) * HH + k, isbf);
                    } else if (g == 3) {
                        if (k < HH) v = loadf(wih2, (size_t)(2 * HH + u) * HH + k, isbf);
                    }
                }
            }
            stg[e] = (_Float16)v;
        }
        __syncthreads();
        if (ps == 0) {
#pragma unroll
            for (int s = 0; s < 3; ++s) if (s < nM1) {
                int tl = bM1 + s;
                WfM1[s][0] = *(const half8*)(stg + (size_t)(16 * tl + n16) * 64 + q * 8);
                WfM1[s][1] = *(const half8*)(stg + (size_t)(16 * tl + n16) * 64 + 32 + q * 8);
            }
        } else if (ps == 1) {
#pragma unroll
            for (int s = 0; s < 3; ++s) if (s < nM2) {
                int tl = bM2 + s;
                WfM2[s][0] = *(const half8*)(stg + (size_t)(16 * tl + n16) * 64 + q * 8);
                WfM2[s][1] = *(const half8*)(stg + (size_t)(16 * tl + n16) * 64 + 32 + q * 8);
            }
        } else {
#pragma unroll
            for (int s = 0; s < 3; ++s) if (s < nM2) {
                int tl = bM2 + s;
                WfM2[s][2] = *(const half8*)(stg + (size_t)(16 * tl + n16) * 64 + q * 8);
                WfM2[s][3] = *(const half8*)(stg + (size_t)(16 * tl + n16) * 64 + 32 + q * 8);
            }
        }
        __syncthreads();
    }

    // ---- init runtime LDS ----
    for (int e = tid; e < 16 * 72; e += TPB) { h1b[e] = (_Float16)0; h2b[e] = (_Float16)0; }
    for (int e = tid; e < 52 * US; e += TPB) { gbuf1[e] = 0.0f; gbuf2[e] = 0.0f; }

    // x prefetch, double-buffered
    float xreg = 0.0f, xnext = 0.0f;
    if (lane < T) xreg = loadf(xg, (size_t)myb * T + lane, isbf);
    __syncthreads();
    if (tid < 16) { h1b[tid * 72 + 52] = (_Float16)1.0f; h2b[tid * 72 + 52] = (_Float16)1.0f; }
    if (lane == 0) h1b[w * 72 + 53] = (_Float16)rdlane(xreg, 0);   // x(0) fold
    __syncthreads();

    // ---- prologue: G1(0) = M1 @ [h1(-1)=0; 1; x(0)] ----
    {
        half8 H10 = *(const half8*)(h1b + n16 * 72 + q * 8);
        half8 H11 = *(const half8*)(h1b + n16 * 72 + 32 + q * 8);
#pragma unroll
        for (int s = 0; s < 3; ++s) if (s < nM1) {
            f4 a = {0.f, 0.f, 0.f, 0.f};
            a = MF(WfM1[s][0], H10, a); a = MF(WfM1[s][1], H11, a);
            if (stlane) *(f4*)(gbuf1 + (bM1 + s) * 4 * US + laneoff) = a;
        }
    }
    __syncthreads();

    float h1p = 0.0f, h2p = 0.0f;
    const float* gl1 = gbuf1 + il * US + 4 * w;
    const float* gl2 = gbuf2 + il * US + 4 * w;
    const int or2 = 51 * US;   // out value at gbuf2[or2 + 4*batch]

    // ================= ENCODE loop =================
    for (int t = 0; t < T; ++t) {
        // ---- P1: e1(t) [pure gate math] + e2(t-1) ----
        f4 G1 = *(const f4*)gl1;
        // x(t+1) fold write (off critical path; 0 at transition)
        {
            int ni = (t + 1) & 63;
            float xsrc = (ni == 0) ? xnext : xreg;
            float xnv = (t == T - 1) ? 0.0f : rdlane(xsrc, ni);
            if (lane == 0) h1b[w * 72 + 53] = (_Float16)xnv;
        }
        {
            float r = sigm(G1[0]);
            float z = sigm(G1[1]);
            float n = tanh_fast(fmaf(r, G1[2], G1[3]));
            float h = fmaf(z, h1p - n, n); h1p = h;
            if (li) h1b[w * 72 + il] = (_Float16)h;
        }
        if (t > 0) {
            f4 G2 = *(const f4*)gl2;
            float r2 = sigm(G2[0]), z2 = sigm(G2[1]);
            float n2 = tanh_fast(fmaf(r2, G2[2], G2[3]));
            float h = fmaf(z2, h2p - n2, n2); h2p = h;
            if (li) h2b[w * 72 + il] = (_Float16)h;
        }
        if (lane == 0 && t >= 2)
            obufL[w * 36 + ((t - 2) & 31)] = gbuf2[or2 + 4 * w];
        LBAR();

        // ---- P2: M1 jobs (2 MFMA) + M2 jobs (4 MFMA, split acc) ----
        {
            half8 H10 = *(const half8*)(h1b + n16 * 72 + q * 8);
            half8 H11 = *(const half8*)(h1b + n16 * 72 + 32 + q * 8);
            half8 H20 = *(const half8*)(h2b + n16 * 72 + q * 8);
            half8 H21 = *(const half8*)(h2b + n16 * 72 + 32 + q * 8);
#pragma unroll
            for (int s = 0; s < 3; ++s) if (s < nM1) {
                f4 a = {0.f, 0.f, 0.f, 0.f};
                a = MF(WfM1[s][0], H10, a); a = MF(WfM1[s][1], H11, a);
                if (stlane) *(f4*)(gbuf1 + (bM1 + s) * 4 * US + laneoff) = a;
            }
#pragma unroll
            for (int s = 0; s < 3; ++s) if (s < nM2) {
                f4 a = {0.f, 0.f, 0.f, 0.f}, b = {0.f, 0.f, 0.f, 0.f};
                a = MF(WfM2[s][0], H20, a); a = MF(WfM2[s][1], H21, a);
                b = MF(WfM2[s][2], H10, b); b = MF(WfM2[s][3], H11, b);
                a = a + b;
                if (stlane) *(f4*)(gbuf2 + (bM2 + s) * 4 * US + laneoff) = a;
            }
        }
        // waves 6,7 flush outputs [t-33 .. t-2]
        if (w >= 6 && (t & 31) == 1 && t > 32) {
            int fb = t - 33;
#pragma unroll
            for (int k2 = 0; k2 < 2; ++k2) {
                int et = ((w - 6) << 7) + (k2 << 6) + lane;
                int b = et >> 5, tt = et & 31;
                storef(dout, (size_t)(bg0 + b) * TF + fb + tt, obufL[b * 36 + tt], isbf);
            }
        }
        // x double-buffer
        if ((t & 63) == 0) {
            int base = t + 64;
            if (base < T) {
                int src = base + lane;
                xnext = (src < T) ? loadf(xg, (size_t)myb * T + src, isbf) : 0.0f;
            }
        } else if ((t & 63) == 63) {
            xreg = xnext;
        }
        LBAR();
    }

    // ================= FEEDBACK loop =================
    for (int t = T; t < TF; ++t) {
        // ---- P1: e2(t-1) -> out(t-1) -> e1(t) (slot53 = 0; explicit x terms) ----
        f4 G1 = *(const f4*)gl1;
        f4 G2 = *(const f4*)gl2;
        if (t == T && lane == 0)   // patch out(T-2) owed by the fold
            obufL[w * 36 + ((t - 2) & 31)] = gbuf2[or2 + 4 * w];
        {
            float r2 = sigm(G2[0]), z2 = sigm(G2[1]);
            float n2 = tanh_fast(fmaf(r2, G2[2], G2[3]));
            float h = fmaf(z2, h2p - n2, n2); h2p = h;
            float p = 0.0f;
            if (li) {
                h2b[w * 72 + il] = (_Float16)h;
                p = h * wl;
            }
            float outv = wave_sum(p) + blv;
            if (lane == 0) obufL[w * 36 + ((t - 1) & 31)] = outv;
            float r = sigm(fmaf(outv, wr1, G1[0]));
            float z = sigm(fmaf(outv, wz1, G1[1]));
            float n = tanh_fast(fmaf(r, G1[2], fmaf(outv, wn1, G1[3])));   // G1[3] = bin
            float h1 = fmaf(z, h1p - n, n); h1p = h1;
            if (li) h1b[w * 72 + il] = (_Float16)h1;
        }
        LBAR();
        // ---- P2 ----
        {
            half8 H10 = *(const half8*)(h1b + n16 * 72 + q * 8);
            half8 H11 = *(const half8*)(h1b + n16 * 72 + 32 + q * 8);
            half8 H20 = *(const half8*)(h2b + n16 * 72 + q * 8);
            half8 H21 = *(const half8*)(h2b + n16 * 72 + 32 + q * 8);
#pragma unroll
            for (int s = 0; s < 3; ++s) if (s < nM1) {
                f4 a = {0.f, 0.f, 0.f, 0.f};
                a = MF(WfM1[s][0], H10, a); a = MF(WfM1[s][1], H11, a);
                if (stlane) *(f4*)(gbuf1 + (bM1 + s) * 4 * US + laneoff) = a;
            }
#pragma unroll
            for (int s = 0; s < 3; ++s) if (s < nM2) {
                f4 a = {0.f, 0.f, 0.f, 0.f}, b = {0.f, 0.f, 0.f, 0.f};
                a = MF(WfM2[s][0], H20, a); a = MF(WfM2[s][1], H21, a);
                b = MF(WfM2[s][2], H10, b); b = MF(WfM2[s][3], H11, b);
                a = a + b;
                if (stlane) *(f4*)(gbuf2 + (bM2 + s) * 4 * US + laneoff) = a;
            }
        }
        if (w >= 6 && (t & 31) == 0) {   // flush [t-32 .. t-1]
            int fb = t - 32;
#pragma unroll
            for (int k2 = 0; k2 < 2; ++k2) {
                int et = ((w - 6) << 7) + (k2 << 6) + lane;
                int b = et >> 5, tt = et & 31;
                storef(dout, (size_t)(bg0 + b) * TF + fb + tt, obufL[b * 36 + tt], isbf);
            }
        }
        LBAR();
    }

    // ---- epilogue: e2(TF-1) + out(TF-1) + tail flush ----
    {
        f4 G2 = *(const f4*)gl2;
        float p = 0.0f;
        float r2 = sigm(G2[0]), z2 = sigm(G2[1]);
        float n2 = tanh_fast(fmaf(r2, G2[2], G2[3]));
        float h = fmaf(z2, h2p - n2, n2);
        if (li) p = h * wl;
        float osum = wave_sum(p) + blv;
        if (lane == 0) obufL[w * 36 + ((TF - 1) & 31)] = osum;
    }
    __syncthreads();
    {
        int base = (TF - 1) & ~31, rem = TF - base;
        if (tid < BPB * 32) {
            int b = tid >> 5, tt = tid & 31;
            if (tt < rem)
                storef(dout, (size_t)(bg0 + b) * TF + base + tt, obufL[b * 36 + tt], isbf);
        }
    }
}

extern "C" void kernel_launch(void* const* d_in, const int* in_sizes, int n_in,
                              void* d_out, int out_size, void* d_ws, size_t ws_size,
                              hipStream_t stream) {
    const int B = 2048;
    const int T = in_sizes[0] / B;   // 1000
    const int TF = out_size / B;     // 2000
    gru_kernel<<<dim3(B / BPB), dim3(TPB), 0, stream>>>(
        d_in[0], d_in[1], d_in[2], d_in[3], d_in[4], d_in[5],
        d_in[6], d_in[7], d_in[8], d_in[9], d_in[10],
        d_out, T, TF);
}

// Round 11
// 1608.675 us; speedup vs baseline: 1.4274x; 1.1084x over previous
//
#include <hip/hip_runtime.h>
#include <hip/hip_bf16.h>

#define HH 51
#define TPB 512     // 8 waves; 1 block/CU. Encode: single fused phase/step. Feedback: R9 2-phase.
#define BPB 8
#define US 36       // unit stride (floats) in gate buffers (feedback path)

typedef _Float16 half8 __attribute__((ext_vector_type(8)));
typedef float f4 __attribute__((ext_vector_type(4)));

// Light barrier: drain LDS only; global stores / reg-dest loads stay in flight.
#define LBAR() asm volatile("s_waitcnt lgkmcnt(0)\ns_barrier" ::: "memory")

__device__ __forceinline__ float bf2f(unsigned short u) {
    return __uint_as_float(((unsigned)u) << 16);
}
__device__ __forceinline__ float loadf(const void* p, size_t i, bool bf) {
    return bf ? bf2f(((const unsigned short*)p)[i]) : ((const float*)p)[i];
}
__device__ __forceinline__ void storef(void* p, size_t i, float v, bool bf) {
    if (bf) ((__hip_bfloat16*)p)[i] = __float2bfloat16(v);
    else    ((float*)p)[i] = v;
}
// 4-instr sigmoid: rcp(1+exp(-v))
__device__ __forceinline__ float sigm(float v) {
    return __builtin_amdgcn_rcpf(1.0f + __expf(-v));
}
// 5-instr tanh: 2*rcp(1+exp(-2v)) - 1
__device__ __forceinline__ float tanh_fast(float v) {
    return fmaf(2.0f, __builtin_amdgcn_rcpf(1.0f + __expf(-2.0f * v)), -1.0f);
}
__device__ __forceinline__ f4 MF(half8 a, half8 b, f4 c) {
    return __builtin_amdgcn_mfma_f32_16x16x32_f16(a, b, c, 0, 0, 0);
}
// wave64 sum via DPP (verified), result uniform across lanes
__device__ __forceinline__ float wave_sum(float x) {
    float s = x, t;
    t = __builtin_bit_cast(float, __builtin_amdgcn_update_dpp(0, __builtin_bit_cast(int, s), 0x111, 0xf, 0xf, true)); s += t;
    t = __builtin_bit_cast(float, __builtin_amdgcn_update_dpp(0, __builtin_bit_cast(int, s), 0x112, 0xf, 0xf, true)); s += t;
    t = __builtin_bit_cast(float, __builtin_amdgcn_update_dpp(0, __builtin_bit_cast(int, s), 0x114, 0xf, 0xf, true)); s += t;
    t = __builtin_bit_cast(float, __builtin_amdgcn_update_dpp(0, __builtin_bit_cast(int, s), 0x118, 0xf, 0xf, true)); s += t;
    t = __builtin_bit_cast(float, __builtin_amdgcn_update_dpp(0, __builtin_bit_cast(int, s), 0x142, 0xa, 0xf, true)); s += t;
    t = __builtin_bit_cast(float, __builtin_amdgcn_update_dpp(0, __builtin_bit_cast(int, s), 0x143, 0xc, 0xf, true)); s += t;
    return __builtin_bit_cast(float, __builtin_amdgcn_readlane(__builtin_bit_cast(int, s), 63));
}
__device__ __forceinline__ float rdlane(float v, int idx) {
    return __builtin_bit_cast(float, __builtin_amdgcn_readlane(__builtin_bit_cast(int, v), idx));
}

__global__ __launch_bounds__(TPB, 1) void gru_kernel(
    const void* __restrict__ xg,
    const void* __restrict__ wih1, const void* __restrict__ whh1,
    const void* __restrict__ bih1, const void* __restrict__ bhh1,
    const void* __restrict__ wih2, const void* __restrict__ whh2,
    const void* __restrict__ bih2, const void* __restrict__ bhh2,
    const void* __restrict__ wlin, const void* __restrict__ blin_p,
    void* __restrict__ dout, int T, int TF)
{
    // Rows 4-interleaved: staged row r = 4*unit + slot.
    //  M1: (r_full, z_full, n_h, n_i) — wih1 col53, biases col52, Whh1 cols 0-50
    //  M2: (r2, z2, n2_h, n2_i) over K=128: [h2|bias ; h1]; out row 204 (wl, blv@52)
    __shared__ __align__(16) _Float16 stg[208 * 64];     // 26624 B
    __shared__ __align__(16) float gbuf1[52 * US];       // feedback gates layer 1
    __shared__ __align__(16) float gbuf2[52 * US];       // feedback gates layer 2 (+ out @ unit 51)
    __shared__ __align__(16) _Float16 h1T[2][16 * 72];   // double-buffered h1; k52=1, k53=x-fold
    __shared__ __align__(16) _Float16 h2T[2][16 * 72];   // double-buffered h2; k52=1
    __shared__ float obufL[BPB * 64];                    // out ring, 64 deep
    __shared__ float hfin[2][BPB * 52];                  // f32 h-state handoff at transition

    const int tid = threadIdx.x, w = tid >> 6, lane = tid & 63;
    const int n16 = lane & 15, q = lane >> 4;
    const bool li = lane < HH;
    const int il = li ? lane : HH - 1;
    const int bg0 = blockIdx.x * BPB;
    const int myb = bg0 + w;

    // runtime dtype detection (fp32 vs bf16), uniform
    bool isbf;
    {
        const unsigned short* u = (const unsigned short*)whh1;
        int ok = 1;
#pragma unroll
        for (int k = 0; k < 16; ++k) {
            unsigned e = (u[2 * k] >> 7) & 0xFF;
            ok &= (e >= 100 && e <= 125) ? 1 : 0;
        }
        isbf = (ok != 0);
    }

    // lane consts (feedback path + out)
    float wr1 = 0, wz1 = 0, wn1 = 0, wl = 0;
    if (li) {
        wr1 = loadf(wih1, il, isbf);          wz1 = loadf(wih1, HH + il, isbf);
        wn1 = loadf(wih1, 2 * HH + il, isbf); wl = loadf(wlin, il, isbf);
    }
    const float blv = loadf(blin_p, 0, isbf);

    // ---- job assignment: 13 M1 + 13 M2 tiles over 8 waves (round-robin) ----
    // w: M1{w, w+8 if w<5}; M2: w<2:{w+3,w+11}, 2<=w<5:{w+3}, w>=5:{w-5,w+3}
    const int nm1 = (w < 5) ? 2 : 1;
    int m2a, m2b, nm2;
    if (w < 2)      { m2a = w + 3; m2b = w + 11; nm2 = 2; }
    else if (w < 5) { m2a = w + 3; m2b = 0;      nm2 = 1; }
    else            { m2a = w - 5; m2b = w + 3;  nm2 = 2; }
    const int m1t[2] = { w, w + 8 };
    const int m2t[2] = { m2a, m2b };
    const int laneoff = q * US + 4 * n16;
    const bool stlane = (n16 < 8);
    const bool outw = (w == 1);   // owns M2 tile 12 (out row) at i==1

    half8 WfM1[2][2], WfM2[2][4];

    // ---- stage: pass0 = M1; pass1 = M2 K 0-63 (h2 half); pass2 = M2 K 64-127 (h1 half) ----
#pragma unroll 1
    for (int ps = 0; ps < 3; ++ps) {
        for (int e = tid; e < 208 * 64; e += TPB) {
            int r = e >> 6, k = e & 63;
            int u = r >> 2, g = r & 3;
            float v = 0.0f;
            if (ps == 0) {
                if (u < HH) {
                    if (g < 2) {
                        int gr = g * HH + u;
                        if (k < HH) v = loadf(whh1, (size_t)gr * HH + k, isbf);
                        else if (k == 52) v = loadf(bhh1, gr, isbf) + loadf(bih1, gr, isbf);
                        else if (k == 53) v = loadf(wih1, gr, isbf);
                    } else if (g == 2) {
                        int gr = 2 * HH + u;
                        if (k < HH) v = loadf(whh1, (size_t)gr * HH + k, isbf);
                        else if (k == 52) v = loadf(bhh1, gr, isbf);
                    } else {
                        int gr = 2 * HH + u;
                        if (k == 52) v = loadf(bih1, gr, isbf);
                        else if (k == 53) v = loadf(wih1, gr, isbf);
                    }
                }
            } else if (ps == 1) {
                if (u < HH) {
                    if (g < 2) {
                        int gr = g * HH + u;
                        if (k < HH) v = loadf(whh2, (size_t)gr * HH + k, isbf);
                        else if (k == 52) v = loadf(bhh2, gr, isbf) + loadf(bih2, gr, isbf);
                    } else if (g == 2) {
                        int gr = 2 * HH + u;
                        if (k < HH) v = loadf(whh2, (size_t)gr * HH + k, isbf);
                        else if (k == 52) v = loadf(bhh2, gr, isbf);
                    } else {
                        if (k == 52) v = loadf(bih2, 2 * HH + u, isbf);
                    }
                } else if (r == 204) {   // out row: wl . h2 + blv
                    if (k < HH) v = loadf(wlin, k, isbf);
                    else if (k == 52) v = blv;
                }
            } else {
                if (u < HH) {
                    if (g < 2) {
                        if (k < HH) v = loadf(wih2, (size_t)(g * HH + u) * HH + k, isbf);
                    } else if (g == 3) {
                        if (k < HH) v = loadf(wih2, (size_t)(2 * HH + u) * HH + k, isbf);
                    }
                }
            }
            stg[e] = (_Float16)v;
        }
        __syncthreads();
        if (ps == 0) {
#pragma unroll
            for (int i = 0; i < 2; ++i) if (i < nm1) {
                int tl = m1t[i];
                WfM1[i][0] = *(const half8*)(stg + (size_t)(16 * tl + n16) * 64 + q * 8);
                WfM1[i][1] = *(const half8*)(stg + (size_t)(16 * tl + n16) * 64 + 32 + q * 8);
            }
        } else if (ps == 1) {
#pragma unroll
            for (int i = 0; i < 2; ++i) if (i < nm2) {
                int tl = m2t[i];
                WfM2[i][0] = *(const half8*)(stg + (size_t)(16 * tl + n16) * 64 + q * 8);
                WfM2[i][1] = *(const half8*)(stg + (size_t)(16 * tl + n16) * 64 + 32 + q * 8);
            }
        } else {
#pragma unroll
            for (int i = 0; i < 2; ++i) if (i < nm2) {
                int tl = m2t[i];
                WfM2[i][2] = *(const half8*)(stg + (size_t)(16 * tl + n16) * 64 + q * 8);
                WfM2[i][3] = *(const half8*)(stg + (size_t)(16 * tl + n16) * 64 + 32 + q * 8);
            }
        }
        __syncthreads();
    }

    // ---- init state LDS ----
    for (int e = tid; e < 16 * 72; e += TPB) {
        h1T[0][e] = (_Float16)0; h1T[1][e] = (_Float16)0;
        h2T[0][e] = (_Float16)0; h2T[1][e] = (_Float16)0;
    }
    float xreg = 0.0f, xnext = 0.0f;
    if (lane < T) xreg = loadf(xg, (size_t)myb * T + lane, isbf);
    __syncthreads();
    if (tid < 16) {
        h1T[0][tid * 72 + 52] = (_Float16)1.0f; h1T[1][tid * 72 + 52] = (_Float16)1.0f;
        h2T[0][tid * 72 + 52] = (_Float16)1.0f; h2T[1][tid * 72 + 52] = (_Float16)1.0f;
    }
    if (lane == 0) h1T[1][w * 72 + 53] = (_Float16)rdlane(xreg, 0);   // x(0) into phase-0 read buffer
    __syncthreads();

    float h1s[2] = {0.f, 0.f}, h2s[2] = {0.f, 0.f};

    // ================= ENCODE: one fused phase per step =================
    // phase t: reads h1T/h2T[(t-1)&1]; M1 -> e1(t) -> h1T[t&1]; M2 -> e2(t-1) -> h2T[t&1]
    for (int t = 0; t < T; ++t) {
        const _Float16* h1r = h1T[(t + 1) & 1];
        const _Float16* h2r = h2T[(t + 1) & 1];
        _Float16* h1w = h1T[t & 1];
        _Float16* h2w = h2T[t & 1];
        half8 H10 = *(const half8*)(h1r + n16 * 72 + q * 8);
        half8 H11 = *(const half8*)(h1r + n16 * 72 + 32 + q * 8);
        half8 H20 = *(const half8*)(h2r + n16 * 72 + q * 8);
        half8 H21 = *(const half8*)(h2r + n16 * 72 + 32 + q * 8);
        // x(t+1) fold into next read buffer
        {
            int ni = (t + 1) & 63;
            float xsrc = (ni == 0) ? xnext : xreg;
            float xnv = (t == T - 1) ? 0.0f : rdlane(xsrc, ni);
            if (lane == 0) h1w[w * 72 + 53] = (_Float16)xnv;
        }
#pragma unroll
        for (int i = 0; i < 2; ++i) if (i < nm1) {
            f4 a = {0.f, 0.f, 0.f, 0.f};
            a = MF(WfM1[i][0], H10, a); a = MF(WfM1[i][1], H11, a);
            float r = sigm(a[0]), z = sigm(a[1]);
            float n = tanh_fast(fmaf(r, a[2], a[3]));
            float h = fmaf(z, h1s[i] - n, n); h1s[i] = h;
            int u = 4 * m1t[i] + q;
            if (n16 < 8 && u < HH) h1w[n16 * 72 + u] = (_Float16)h;
        }
#pragma unroll
        for (int i = 0; i < 2; ++i) if (i < nm2) {
            f4 a = {0.f, 0.f, 0.f, 0.f}, b = {0.f, 0.f, 0.f, 0.f};
            a = MF(WfM2[i][0], H20, a); a = MF(WfM2[i][1], H21, a);
            b = MF(WfM2[i][2], H10, b); b = MF(WfM2[i][3], H11, b);
            a = a + b;
            if (t > 0) {
                if (outw && i == 1 && q == 3 && n16 < 8 && t >= 2)
                    obufL[n16 * 64 + ((t - 2) & 63)] = a[0];   // out(t-2) from fold row
                float r2 = sigm(a[0]), z2 = sigm(a[1]);
                float n2 = tanh_fast(fmaf(r2, a[2], a[3]));
                float h = fmaf(z2, h2s[i] - n2, n2); h2s[i] = h;
                int u = 4 * m2t[i] + q;
                if (n16 < 8 && u < HH) h2w[n16 * 72 + u] = (_Float16)h;
            }
        }
        // waves 6,7 flush outputs [t-34 .. t-3] (all written by phase t-1 or earlier)
        if (w >= 6 && (t & 31) == 2 && t >= 34) {
            int fb = t - 34;
#pragma unroll
            for (int k2 = 0; k2 < 2; ++k2) {
                int et = ((w - 6) << 7) + (k2 << 6) + lane;
                int b2 = et >> 5, tt = et & 31;
                storef(dout, (size_t)(bg0 + b2) * TF + fb + tt, obufL[b2 * 64 + ((fb + tt) & 63)], isbf);
            }
        }
        // x double-buffer
        if ((t & 63) == 0) {
            int base = t + 64;
            if (base < T) {
                int src = base + lane;
                xnext = (src < T) ? loadf(xg, (size_t)myb * T + src, isbf) : 0.0f;
            }
        } else if ((t & 63) == 63) {
            xreg = xnext;
        }
        LBAR();
    }

    // ================= TRANSITION: populate gbuf + f32 h-state handoff =================
    const int fbi = (T + 1) & 1;   // (T-1)&1
    {
        const _Float16* h1r = h1T[fbi];
        const _Float16* h2r = h2T[fbi];
        half8 H10 = *(const half8*)(h1r + n16 * 72 + q * 8);
        half8 H11 = *(const half8*)(h1r + n16 * 72 + 32 + q * 8);
        half8 H20 = *(const half8*)(h2r + n16 * 72 + q * 8);
        half8 H21 = *(const half8*)(h2r + n16 * 72 + 32 + q * 8);
#pragma unroll
        for (int i = 0; i < 2; ++i) if (i < nm1) {
            f4 a = {0.f, 0.f, 0.f, 0.f};
            a = MF(WfM1[i][0], H10, a); a = MF(WfM1[i][1], H11, a);
            if (stlane) *(f4*)(gbuf1 + m1t[i] * 4 * US + laneoff) = a;   // G1(T)
            int u = 4 * m1t[i] + q;
            if (n16 < 8 && u < HH) hfin[0][n16 * 52 + u] = h1s[i];       // h1(T-1) f32
        }
#pragma unroll
        for (int i = 0; i < 2; ++i) if (i < nm2) {
            f4 a = {0.f, 0.f, 0.f, 0.f}, b = {0.f, 0.f, 0.f, 0.f};
            a = MF(WfM2[i][0], H20, a); a = MF(WfM2[i][1], H21, a);
            b = MF(WfM2[i][2], H10, b); b = MF(WfM2[i][3], H11, b);
            a = a + b;
            if (stlane) *(f4*)(gbuf2 + m2t[i] * 4 * US + laneoff) = a;   // G2(T-1) + out row
            int u = 4 * m2t[i] + q;
            if (n16 < 8 && u < HH) hfin[1][n16 * 52 + u] = h2s[i];       // h2(T-2) f32
        }
    }
    __syncthreads();

    float h1p = hfin[0][w * 52 + il];   // h1(T-1)
    float h2p = hfin[1][w * 52 + il];   // h2(T-2)
    const float* gl1 = gbuf1 + il * US + 4 * w;
    const float* gl2 = gbuf2 + il * US + 4 * w;
    const int or2 = 51 * US;
    _Float16* fh1 = h1T[fbi];
    _Float16* fh2 = h2T[fbi];

    // ================= FEEDBACK: 2 phases/step (R9 structure) =================
    for (int t = T; t < TF; ++t) {
        // ---- P1: e2(t-1) -> out(t-1) -> e1(t) ----
        f4 G1 = *(const f4*)gl1;
        f4 G2 = *(const f4*)gl2;
        if (t == T && lane == 0)   // patch out(T-2) from the fold row
            obufL[w * 64 + ((t - 2) & 63)] = gbuf2[or2 + 4 * w];
        {
            float r2 = sigm(G2[0]), z2 = sigm(G2[1]);
            float n2 = tanh_fast(fmaf(r2, G2[2], G2[3]));
            float h = fmaf(z2, h2p - n2, n2); h2p = h;
            float p = 0.0f;
            if (li) {
                fh2[w * 72 + il] = (_Float16)h;
                p = h * wl;
            }
            float outv = wave_sum(p) + blv;
            if (lane == 0) obufL[w * 64 + ((t - 1) & 63)] = outv;
            float r = sigm(fmaf(outv, wr1, G1[0]));
            float z = sigm(fmaf(outv, wz1, G1[1]));
            float n = tanh_fast(fmaf(r, G1[2], fmaf(outv, wn1, G1[3])));   // G1[3] = bin
            float h1 = fmaf(z, h1p - n, n); h1p = h1;
            if (li) fh1[w * 72 + il] = (_Float16)h1;
        }
        LBAR();
        // ---- P2: matmuls -> gbuf ----
        {
            half8 H10 = *(const half8*)(fh1 + n16 * 72 + q * 8);
            half8 H11 = *(const half8*)(fh1 + n16 * 72 + 32 + q * 8);
            half8 H20 = *(const half8*)(fh2 + n16 * 72 + q * 8);
            half8 H21 = *(const half8*)(fh2 + n16 * 72 + 32 + q * 8);
#pragma unroll
            for (int i = 0; i < 2; ++i) if (i < nm1) {
                f4 a = {0.f, 0.f, 0.f, 0.f};
                a = MF(WfM1[i][0], H10, a); a = MF(WfM1[i][1], H11, a);
                if (stlane) *(f4*)(gbuf1 + m1t[i] * 4 * US + laneoff) = a;
            }
#pragma unroll
            for (int i = 0; i < 2; ++i) if (i < nm2) {
                f4 a = {0.f, 0.f, 0.f, 0.f}, b = {0.f, 0.f, 0.f, 0.f};
                a = MF(WfM2[i][0], H20, a); a = MF(WfM2[i][1], H21, a);
                b = MF(WfM2[i][2], H10, b); b = MF(WfM2[i][3], H11, b);
                a = a + b;
                if (stlane) *(f4*)(gbuf2 + m2t[i] * 4 * US + laneoff) = a;
            }
        }
        if (w >= 6 && (t & 31) == 0) {   // flush [t-32 .. t-1]
            int fb = t - 32;
#pragma unroll
            for (int k2 = 0; k2 < 2; ++k2) {
                int et = ((w - 6) << 7) + (k2 << 6) + lane;
                int b2 = et >> 5, tt = et & 31;
                storef(dout, (size_t)(bg0 + b2) * TF + fb + tt, obufL[b2 * 64 + ((fb + tt) & 63)], isbf);
            }
        }
        LBAR();
    }

    // ---- epilogue: e2(TF-1) + out(TF-1) + tail flush ----
    {
        f4 G2 = *(const f4*)gl2;
        float p = 0.0f;
        float r2 = sigm(G2[0]), z2 = sigm(G2[1]);
        float n2 = tanh_fast(fmaf(r2, G2[2], G2[3]));
        float h = fmaf(z2, h2p - n2, n2);
        if (li) p = h * wl;
        float osum = wave_sum(p) + blv;
        if (lane == 0) obufL[w * 64 + ((TF - 1) & 63)] = osum;
    }
    __syncthreads();
    {
        int base = (TF - 1) & ~31, rem = TF - base;
        if (tid < BPB * 32) {
            int b2 = tid >> 5, tt = tid & 31;
            if (tt < rem)
                storef(dout, (size_t)(bg0 + b2) * TF + base + tt, obufL[b2 * 64 + ((base + tt) & 63)], isbf);
        }
    }
}

extern "C" void kernel_launch(void* const* d_in, const int* in_sizes, int n_in,
                              void* d_out, int out_size, void* d_ws, size_t ws_size,
                              hipStream_t stream) {
    const int B = 2048;
    const int T = in_sizes[0] / B;   // 1000
    const int TF = out_size / B;     // 2000
    gru_kernel<<<dim3(B / BPB), dim3(TPB), 0, stream>>>(
        d_in[0], d_in[1], d_in[2], d_in[3], d_in[4], d_in[5],
        d_in[6], d_in[7], d_in[8], d_in[9], d_in[10],
        d_out, T, TF);
}